// Round 1
// baseline (489.455 us; speedup 1.0000x reference)
//
#include <hip/hip_runtime.h>

// LSTM: B=4096, T=512, I=1, H=32.  One wave (64 lanes) per batch element.
// Lane t owns gate rows t (g0: i/f) and t+64 (g1: g/o) of the 4H=128 gates.
// h[k] replicated in lanes k and k+32; broadcast via v_readlane (SGPR operand).
// No LDS, no barriers, fp32 throughout.

#define L2E 1.44269504088896340736f

__device__ __forceinline__ float readlane_f(float v, int l) {
    return __uint_as_float(__builtin_amdgcn_readlane(__float_as_uint(v), (unsigned)l));
}

__device__ __forceinline__ float fast_sigmoid(float x) {
    // sigmoid(x) = 1 / (1 + 2^(-x*log2(e)))
    float e = __builtin_amdgcn_exp2f(-x * L2E);
    return __builtin_amdgcn_rcpf(1.0f + e);
}

__global__ __launch_bounds__(256, 4) void lstm_fused_kernel(
    const float* __restrict__ x,      // [B, T]  (I==1)
    const float* __restrict__ W_ih,   // [128]   (4H x 1)
    const float* __restrict__ W_hh,   // [128, 32]
    const float* __restrict__ b_ih,   // [128]
    const float* __restrict__ b_hh,   // [128]
    const float* __restrict__ W_lin,  // [32]    (1 x H)
    const float* __restrict__ b_lin,  // [1]
    float* __restrict__ out,          // [B]
    int B)
{
    const int lane = (int)(threadIdx.x & 63u);
    const int wid  = (int)(threadIdx.x >> 6);
    const int b    = blockIdx.x * 4 + wid;
    if (b >= B) return;

    const int t_lo = lane;         // gate row for g0 (i: 0..31, f: 32..63)
    const int t_hi = lane + 64;    // gate row for g1 (g: 64..95, o: 96..127)

    // W_hh rows into registers (64 VGPRs), vectorized float4 loads.
    float wlo[32], whi[32];
#pragma unroll
    for (int j = 0; j < 32; j += 4) {
        float4 v0 = *reinterpret_cast<const float4*>(&W_hh[t_lo * 32 + j]);
        wlo[j + 0] = v0.x; wlo[j + 1] = v0.y; wlo[j + 2] = v0.z; wlo[j + 3] = v0.w;
        float4 v1 = *reinterpret_cast<const float4*>(&W_hh[t_hi * 32 + j]);
        whi[j + 0] = v1.x; whi[j + 1] = v1.y; whi[j + 2] = v1.z; whi[j + 3] = v1.w;
    }

    const float bias0 = b_ih[t_lo] + b_hh[t_lo];
    const float bias1 = b_ih[t_hi] + b_hh[t_hi];
    const float wih0  = W_ih[t_lo];
    const float wih1  = W_ih[t_hi];

    const bool  isLo   = lane < 32;
    // g1 nonlinearity: lanes<32 -> tanh (g gate), lanes>=32 -> sigmoid (o gate).
    // tanh(x) = 2*sigmoid(2x) - 1; both forms: r = rcp(1 + 2^(x*mscale)); a = r*pm + pa
    const float mscale = isLo ? (-2.0f * L2E) : (-L2E);
    const float pm     = isLo ? 2.0f : 1.0f;
    const float pa     = isLo ? -1.0f : 0.0f;

    float h = 0.0f, c = 0.0f;

    const float* xb = x + (size_t)b * 512;

    for (int chunk = 0; chunk < 8; ++chunk) {
        const float xv = xb[chunk * 64 + lane];  // 64 timesteps of x, one per lane
#pragma unroll 4
        for (int m = 0; m < 64; ++m) {
            const float xt = readlane_f(xv, m);

            float g0 = fmaf(xt, wih0, bias0);
            float g1 = fmaf(xt, wih1, bias1);
#pragma unroll
            for (int j = 0; j < 32; ++j) {
                const float hj = readlane_f(h, j);
                g0 = fmaf(hj, wlo[j], g0);
                g1 = fmaf(hj, whi[j], g1);
            }

            // a0 = sigmoid(g0): i (lanes<32) / f (lanes>=32)
            const float a0 = fast_sigmoid(g0);
            // a1: tanh(g1) for lanes<32 (g gate), sigmoid(g1) for lanes>=32 (o gate)
            const float e1 = __builtin_amdgcn_exp2f(g1 * mscale);
            const float r1 = __builtin_amdgcn_rcpf(1.0f + e1);
            const float a1 = fmaf(r1, pm, pa);

            const float a0s = __shfl_xor(a0, 32, 64);
            const float a1s = __shfl_xor(a1, 32, 64);

            const float i_ = isLo ? a0  : a0s;
            const float f_ = isLo ? a0s : a0;
            const float g_ = isLo ? a1  : a1s;
            const float o_ = isLo ? a1s : a1;

            c = fmaf(f_, c, i_ * g_);

            // tanh(c)
            const float ec = __builtin_amdgcn_exp2f(c * (-2.0f * L2E));
            const float rc = __builtin_amdgcn_rcpf(1.0f + ec);
            const float tc = fmaf(rc, 2.0f, -1.0f);

            h = o_ * tc;
        }
    }

    // out[b] = dot(h, W_lin) + b_lin ; h replicated in both halves -> zero the hi half
    float part = isLo ? h * W_lin[lane] : 0.0f;
#pragma unroll
    for (int off = 16; off; off >>= 1) part += __shfl_xor(part, off, 64);
    if (lane == 0) out[b] = part + b_lin[0];
}

extern "C" void kernel_launch(void* const* d_in, const int* in_sizes, int n_in,
                              void* d_out, int out_size, void* d_ws, size_t ws_size,
                              hipStream_t stream) {
    const float* x     = (const float*)d_in[0];
    const float* W_ih  = (const float*)d_in[1];
    const float* W_hh  = (const float*)d_in[2];
    const float* b_ih  = (const float*)d_in[3];
    const float* b_hh  = (const float*)d_in[4];
    const float* W_lin = (const float*)d_in[5];
    const float* b_lin = (const float*)d_in[6];
    float* out = (float*)d_out;

    const int B = in_sizes[0] / 512;   // x is [B, 512, 1]
    const int blocks = (B + 3) / 4;    // 4 batch elements (waves) per block

    lstm_fused_kernel<<<blocks, 256, 0, stream>>>(x, W_ih, W_hh, b_ih, b_hh,
                                                  W_lin, b_lin, out, B);
}

// Round 2
// 305.363 us; speedup vs baseline: 1.6029x; 1.6029x over previous
//
#include <hip/hip_runtime.h>

// LSTM: B=4096, T=512, I=1, H=32.  One wave (64 lanes) per batch element.
// Lane t owns gate rows t (g0: i/f) and t+64 (g1: g/o) of the 4H=128 gates.
// h broadcast via LDS (ds_write_b32 + 8x ds_read_b128), matvec via v_pk_fma_f32
// on even/odd j-pairs (natural pairs, no splats). All fp32, no barriers.

typedef float v2f __attribute__((ext_vector_type(2)));

#define L2E 1.44269504088896340736f

__device__ __forceinline__ float readlane_f(float v, int l) {
    return __uint_as_float(__builtin_amdgcn_readlane(__float_as_uint(v), (unsigned)l));
}

__device__ __forceinline__ v2f pkfma(v2f a, v2f b, v2f c) {
    return __builtin_elementwise_fma(a, b, c);
}

__global__ __launch_bounds__(256, 4) void lstm_fused_kernel(
    const float* __restrict__ x,      // [B, T]  (I==1)
    const float* __restrict__ W_ih,   // [128]
    const float* __restrict__ W_hh,   // [128, 32]
    const float* __restrict__ b_ih,   // [128]
    const float* __restrict__ b_hh,   // [128]
    const float* __restrict__ W_lin,  // [32]
    const float* __restrict__ b_lin,  // [1]
    float* __restrict__ out,          // [B]
    int B)
{
    __shared__ float hbuf[4][64];     // per-wave h row (slots 32..63 are dups)

    const int lane = (int)(threadIdx.x & 63u);
    const int wid  = (int)(threadIdx.x >> 6);
    const int b    = blockIdx.x * 4 + wid;
    if (b >= B) return;

    const int t_lo = lane;         // gate row for g0 (i: 0..31, f: 32..63)
    const int t_hi = lane + 64;    // gate row for g1 (g: 64..95, o: 96..127)

    // W_hh rows as even/odd pairs (64 VGPRs total).
    v2f wlo2[16], whi2[16];
#pragma unroll
    for (int k = 0; k < 8; ++k) {
        float4 v0 = *reinterpret_cast<const float4*>(&W_hh[t_lo * 32 + k * 4]);
        wlo2[2 * k + 0] = v2f{v0.x, v0.y};
        wlo2[2 * k + 1] = v2f{v0.z, v0.w};
        float4 v1 = *reinterpret_cast<const float4*>(&W_hh[t_hi * 32 + k * 4]);
        whi2[2 * k + 0] = v2f{v1.x, v1.y};
        whi2[2 * k + 1] = v2f{v1.z, v1.w};
    }

    const float bias0 = b_ih[t_lo] + b_hh[t_lo];
    const float bias1 = b_ih[t_hi] + b_hh[t_hi];
    const float wih0  = W_ih[t_lo];
    const float wih1  = W_ih[t_hi];

    const bool isLo = lane < 32;
    // a0 = sigmoid(g0) for all lanes.
    // a1 = tanh(g1) (lanes<32, g gate) or sigmoid(g1) (lanes>=32, o gate).
    // Both: r = rcp(1 + 2^(g*msc)); a = r*pm + pa   (per-lane packed constants)
    const v2f msc01 = { -L2E, isLo ? (-2.0f * L2E) : (-L2E) };
    const v2f pm01  = { 1.0f, isLo ? 2.0f : 1.0f };
    const v2f pa01  = { 0.0f, isLo ? -1.0f : 0.0f };

    float h = 0.0f, c = 0.0f;
    const float* xb = x + (size_t)b * 512;
    float* hrow = &hbuf[wid][0];

    for (int chunk = 0; chunk < 8; ++chunk) {
        const float xv = xb[chunk * 64 + lane];  // 64 timesteps of x, one per lane
#pragma unroll 4
        for (int m = 0; m < 64; ++m) {
            const float xt = readlane_f(xv, m);

            // publish h(t-1) to this wave's LDS row; in-order DS pipe makes the
            // subsequent reads see it (wave-synchronous, no barrier needed).
            hrow[lane] = h;
            __builtin_amdgcn_wave_barrier();

            const float4* hq = reinterpret_cast<const float4*>(hrow);
            v2f acc0a = {0.f, 0.f}, acc1a = {0.f, 0.f};
            v2f acc0b = {0.f, 0.f}, acc1b = {0.f, 0.f};
#pragma unroll
            for (int q = 0; q < 8; ++q) {
                float4 hv = hq[q];                 // ds_read_b128: h[4q..4q+3]
                v2f hA = {hv.x, hv.y};
                v2f hB = {hv.z, hv.w};
                acc0a = pkfma(hA, wlo2[2 * q + 0], acc0a);
                acc1a = pkfma(hA, whi2[2 * q + 0], acc1a);
                acc0b = pkfma(hB, wlo2[2 * q + 1], acc0b);
                acc1b = pkfma(hB, whi2[2 * q + 1], acc1b);
            }
            acc0a = acc0a + acc0b;                 // pk add
            acc1a = acc1a + acc1b;                 // pk add
            const float g0 = (acc0a.x + acc0a.y) + fmaf(xt, wih0, bias0);
            const float g1 = (acc1a.x + acc1a.y) + fmaf(xt, wih1, bias1);

            // packed gate nonlinearity
            v2f g01 = { g0, g1 };
            v2f tt  = g01 * msc01;                 // pk mul
            v2f ee  = { __builtin_amdgcn_exp2f(tt.x), __builtin_amdgcn_exp2f(tt.y) };
            v2f dd  = ee + 1.0f;                   // pk add
            v2f rr  = { __builtin_amdgcn_rcpf(dd.x), __builtin_amdgcn_rcpf(dd.y) };
            v2f a01 = pkfma(rr, pm01, pa01);

            const float a0s = __shfl_xor(a01.x, 32, 64);
            const float a1s = __shfl_xor(a01.y, 32, 64);

            const float i_ = isLo ? a01.x : a0s;
            const float f_ = isLo ? a0s   : a01.x;
            const float g_ = isLo ? a01.y : a1s;
            const float o_ = isLo ? a1s   : a01.y;

            c = fmaf(f_, c, i_ * g_);

            const float ec = __builtin_amdgcn_exp2f(c * (-2.0f * L2E));
            const float rc = __builtin_amdgcn_rcpf(1.0f + ec);
            const float tc = fmaf(rc, 2.0f, -1.0f);

            h = o_ * tc;
        }
    }

    // out[b] = dot(h, W_lin) + b_lin ; h replicated in both halves -> zero hi half
    float part = isLo ? h * W_lin[lane] : 0.0f;
#pragma unroll
    for (int off = 16; off; off >>= 1) part += __shfl_xor(part, off, 64);
    if (lane == 0) out[b] = part + b_lin[0];
}

extern "C" void kernel_launch(void* const* d_in, const int* in_sizes, int n_in,
                              void* d_out, int out_size, void* d_ws, size_t ws_size,
                              hipStream_t stream) {
    const float* x     = (const float*)d_in[0];
    const float* W_ih  = (const float*)d_in[1];
    const float* W_hh  = (const float*)d_in[2];
    const float* b_ih  = (const float*)d_in[3];
    const float* b_hh  = (const float*)d_in[4];
    const float* W_lin = (const float*)d_in[5];
    const float* b_lin = (const float*)d_in[6];
    float* out = (float*)d_out;

    const int B = in_sizes[0] / 512;   // x is [B, 512, 1]
    const int blocks = (B + 3) / 4;    // 4 batch elements (waves) per block

    lstm_fused_kernel<<<blocks, 256, 0, stream>>>(x, W_ih, W_hh, b_ih, b_hh,
                                                  W_lin, b_lin, out, B);
}

// Round 5
// 295.324 us; speedup vs baseline: 1.6573x; 1.0340x over previous
//
#include <hip/hip_runtime.h>

// LSTM: B=4096, T=512, I=1, H=32.  One wave (64 lanes) per batch element.
// Lane t owns gate rows t (g0: i/f) and t+64 (g1: g/o) of the 4H=128 gates.
// h broadcast via LDS (ds_write_b32 + 8x ds_read_b128).
// Matvec forced to v_pk_fma_f32 via inline asm (fp32 peak requires pk ops).
// Gate half-exchange via __builtin_amdgcn_permlane32_swap — the BUILTIN, not
// inline asm: rounds 3/4 failed because hand-written asm around the permlane
// misses the required VALU-write -> permlane-read hazard wait states (and r3
// additionally let regalloc coalesce the two operands into one register).
// The builtin lets the compiler handle allocation + hazards.

typedef float v2f __attribute__((ext_vector_type(2)));
typedef unsigned int v2u __attribute__((ext_vector_type(2)));

#define L2E 1.44269504088896340736f

__device__ __forceinline__ float readlane_f(float v, int l) {
    return __uint_as_float(__builtin_amdgcn_readlane(__float_as_uint(v), (unsigned)l));
}

__device__ __forceinline__ v2f pkfma(v2f a, v2f b, v2f c) {
    v2f d;
    asm("v_pk_fma_f32 %0, %1, %2, %3" : "=v"(d) : "v"(a), "v"(b), "v"(c));
    return d;
}

// With both inputs = x:
//   lo_all[lane] = x[lane & 31]        (low-half-origin value, in all lanes)
//   hi_all[lane] = x[32 + (lane & 31)] (high-half-origin value, in all lanes)
#if __has_builtin(__builtin_amdgcn_permlane32_swap)
__device__ __forceinline__ void swap_pair(float x, float& lo_all, float& hi_all) {
    const unsigned xu = __float_as_uint(x);
    v2u r = __builtin_amdgcn_permlane32_swap(xu, xu, false, false);
    lo_all = __uint_as_float(r.x);
    hi_all = __uint_as_float(r.y);
}
#else
__device__ __forceinline__ void swap_pair(float x, float& lo_all, float& hi_all) {
    const float xs = __shfl_xor(x, 32, 64);
    const bool isLo = ((int)(threadIdx.x & 63u)) < 32;
    lo_all = isLo ? x : xs;
    hi_all = isLo ? xs : x;
}
#endif

__global__ __launch_bounds__(256, 4) void lstm_fused_kernel(
    const float* __restrict__ x,      // [B, T]  (I==1)
    const float* __restrict__ W_ih,   // [128]
    const float* __restrict__ W_hh,   // [128, 32]
    const float* __restrict__ b_ih,   // [128]
    const float* __restrict__ b_hh,   // [128]
    const float* __restrict__ W_lin,  // [32]
    const float* __restrict__ b_lin,  // [1]
    float* __restrict__ out,          // [B]
    int B)
{
    __shared__ float hbuf[4][64];     // per-wave h row (slots 32..63 are dups)

    const int lane = (int)(threadIdx.x & 63u);
    const int wid  = (int)(threadIdx.x >> 6);
    const int b    = blockIdx.x * 4 + wid;
    if (b >= B) return;

    const int t_lo = lane;         // gate row for g0 (i: 0..31, f: 32..63)
    const int t_hi = lane + 64;    // gate row for g1 (g: 64..95, o: 96..127)

    // W_hh rows as even/odd pairs (64 VGPRs total).
    v2f wlo2[16], whi2[16];
#pragma unroll
    for (int k = 0; k < 8; ++k) {
        float4 v0 = *reinterpret_cast<const float4*>(&W_hh[t_lo * 32 + k * 4]);
        wlo2[2 * k + 0] = v2f{v0.x, v0.y};
        wlo2[2 * k + 1] = v2f{v0.z, v0.w};
        float4 v1 = *reinterpret_cast<const float4*>(&W_hh[t_hi * 32 + k * 4]);
        whi2[2 * k + 0] = v2f{v1.x, v1.y};
        whi2[2 * k + 1] = v2f{v1.z, v1.w};
    }

    const float bias0 = b_ih[t_lo] + b_hh[t_lo];
    const float bias1 = b_ih[t_hi] + b_hh[t_hi];
    const float wih0  = W_ih[t_lo];
    const float wih1  = W_ih[t_hi];

    const bool isLo = lane < 32;
    // a0 = sigmoid(g0) for all lanes (i-rows low half, f-rows high half).
    // a1 = tanh(g1) (lanes<32, g gate) or sigmoid(g1) (lanes>=32, o gate).
    // Both via r = rcp(1 + 2^(g*msc)); a = r*pm + pa  (per-lane constants)
    const float msc1 = isLo ? (-2.0f * L2E) : (-L2E);
    const float pm1  = isLo ? 2.0f : 1.0f;
    const float pa1  = isLo ? -1.0f : 0.0f;

    float h = 0.0f, c = 0.0f;
    const float* xb = x + (size_t)b * 512;
    float* hrow = &hbuf[wid][0];

    for (int chunk = 0; chunk < 8; ++chunk) {
        const float xv = xb[chunk * 64 + lane];  // 64 timesteps of x, one per lane
#pragma unroll 4
        for (int m = 0; m < 64; ++m) {
            const float xt = readlane_f(xv, m);

            // publish h(t-1) to this wave's LDS row (wave-synchronous, in-order
            // DS pipe; wave_barrier only fences compile-time reordering).
            hrow[lane] = h;
            __builtin_amdgcn_wave_barrier();

            const float4* hq = reinterpret_cast<const float4*>(hrow);
            v2f acc0a = {0.f, 0.f}, acc1a = {0.f, 0.f};
            v2f acc0b = {0.f, 0.f}, acc1b = {0.f, 0.f};
#pragma unroll
            for (int q = 0; q < 8; ++q) {
                float4 hv = hq[q];                 // ds_read_b128: h[4q..4q+3]
                v2f hA = {hv.x, hv.y};
                v2f hB = {hv.z, hv.w};
                acc0a = pkfma(hA, wlo2[2 * q + 0], acc0a);
                acc1a = pkfma(hA, whi2[2 * q + 0], acc1a);
                acc0b = pkfma(hB, wlo2[2 * q + 1], acc0b);
                acc1b = pkfma(hB, whi2[2 * q + 1], acc1b);
            }
            v2f acc0 = acc0a + acc0b;
            v2f acc1 = acc1a + acc1b;
            const float g0 = (acc0.x + acc0.y) + fmaf(xt, wih0, bias0);
            const float g1 = (acc1.x + acc1.y) + fmaf(xt, wih1, bias1);

            // gate nonlinearities (round-2 proven scalar path)
            const float e0 = __builtin_amdgcn_exp2f(g0 * (-L2E));
            const float a0 = __builtin_amdgcn_rcpf(1.0f + e0);
            const float e1 = __builtin_amdgcn_exp2f(g1 * msc1);
            const float r1 = __builtin_amdgcn_rcpf(1.0f + e1);
            const float a1 = fmaf(r1, pm1, pa1);

            // one permlane32_swap per gate pair -> i,f,g,o valid in ALL lanes
            float i_, f_, g_, o_;
            swap_pair(a0, i_, f_);
            swap_pair(a1, g_, o_);

            c = fmaf(f_, c, i_ * g_);

            const float ec = __builtin_amdgcn_exp2f(c * (-2.0f * L2E));
            const float rc = __builtin_amdgcn_rcpf(1.0f + ec);
            const float tc = fmaf(rc, 2.0f, -1.0f);

            h = o_ * tc;
        }
    }

    // out[b] = dot(h, W_lin) + b_lin ; h replicated in both halves -> zero hi half
    float part = isLo ? h * W_lin[lane] : 0.0f;
#pragma unroll
    for (int off = 16; off; off >>= 1) part += __shfl_xor(part, off, 64);
    if (lane == 0) out[b] = part + b_lin[0];
}

extern "C" void kernel_launch(void* const* d_in, const int* in_sizes, int n_in,
                              void* d_out, int out_size, void* d_ws, size_t ws_size,
                              hipStream_t stream) {
    const float* x     = (const float*)d_in[0];
    const float* W_ih  = (const float*)d_in[1];
    const float* W_hh  = (const float*)d_in[2];
    const float* b_ih  = (const float*)d_in[3];
    const float* b_hh  = (const float*)d_in[4];
    const float* W_lin = (const float*)d_in[5];
    const float* b_lin = (const float*)d_in[6];
    float* out = (float*)d_out;

    const int B = in_sizes[0] / 512;   // x is [B, 512, 1]
    const int blocks = (B + 3) / 4;    // 4 batch elements (waves) per block

    lstm_fused_kernel<<<blocks, 256, 0, stream>>>(x, W_ih, W_hh, b_ih, b_hh,
                                                  W_lin, b_lin, out, B);
}

// Round 6
// 251.101 us; speedup vs baseline: 1.9492x; 1.1761x over previous
//
#include <hip/hip_runtime.h>

// LSTM B=4096, T=512, I=1, H=32 — MFMA restructure.
//
// One wave = 4 batches. Per step, gates G[4,128] = H[4,32] @ W_hh^T via
// mfma_f32_16x16x32_bf16 (8 col-tiles x 3 hi/lo-split MFMAs, bias in C).
// Batches live in D-rows {0,4,8,12} => row = (lane>>4)*4 + reg means ONLY
// reg 0 is live, and lane l owns batch (l>>4), cells (l&15) and (l&15)+16.
// Tiles 0..7 give [i(c0),i(c1),f(c0),f(c1),g(c0),g(c1),o(c0),o(c1)] all in
// the SAME lane -> cell update is lane-local (no shuffles, no barriers).
// h(t) -> next A-fragment goes through a wave-private LDS tile (rows = A-rows
// 0,4,8,12 live; other A-rows read a shared zero row).
//
// Precision: x = x_hi + x_lo bf16 split for both H and W; compute
// Ahi*Bhi + Ahi*Blo + Alo*Bhi (drop lo*lo ~2^-16) -> gate err ~1e-4.

typedef float f32x4 __attribute__((ext_vector_type(4)));
typedef short s16x8 __attribute__((ext_vector_type(8)));
typedef int   i32x4 __attribute__((ext_vector_type(4)));

union PK { i32x4 i; s16x8 s; };

#define L2E 1.44269504088896340736f

// one u32 = [bf16(lo_f) | bf16(hi_f)<<16]  (truncation; residual captured in lo part)
__device__ __forceinline__ unsigned bfpack(float a, float b) {
    // dst bytes = [a.b2, a.b3, b.b2, b.b3] ; perm src = (arg0:arg1), sel idx 0-3 from arg1
    return __builtin_amdgcn_perm(__float_as_uint(b), __float_as_uint(a), 0x07060302u);
}
__device__ __forceinline__ float hi_f(float f) {
    return __uint_as_float(__float_as_uint(f) & 0xFFFF0000u);
}
// 8 fp32 -> bf16 hi-frag + bf16 lo-frag (element e <-> k = kbase + e; any HW
// k-permutation cancels because A and B are packed with the same function)
__device__ __forceinline__ void split_pack(float4 A, float4 B, s16x8& hi, s16x8& lo) {
    PK h, l;
    h.i = i32x4{(int)bfpack(A.x, A.y), (int)bfpack(A.z, A.w),
                (int)bfpack(B.x, B.y), (int)bfpack(B.z, B.w)};
    l.i = i32x4{(int)bfpack(A.x - hi_f(A.x), A.y - hi_f(A.y)),
                (int)bfpack(A.z - hi_f(A.z), A.w - hi_f(A.w)),
                (int)bfpack(B.x - hi_f(B.x), B.y - hi_f(B.y)),
                (int)bfpack(B.z - hi_f(B.z), B.w - hi_f(B.w))};
    hi = h.s; lo = l.s;
}

__device__ __forceinline__ float sigf(float x) {
    return __builtin_amdgcn_rcpf(1.0f + __builtin_amdgcn_exp2f(-x * L2E));
}
__device__ __forceinline__ float tanh_f(float x) {
    return fmaf(__builtin_amdgcn_rcpf(1.0f + __builtin_amdgcn_exp2f(x * (-2.0f * L2E))),
                2.0f, -1.0f);
}

#define MFMA(a, b, c) __builtin_amdgcn_mfma_f32_16x16x32_bf16((a), (b), (c), 0, 0, 0)

// LDS H-tile row stride 36 floats: 16B-aligned (144B) and banks spread
// (srow*36 + kbase) % 32 distinct per srow -> conflict-free-ish A reads.
#define HSTRIDE 36

__global__ __launch_bounds__(256, 1) void lstm_mfma_kernel(
    const float* __restrict__ x,      // [B, 512]
    const float* __restrict__ W_ih,   // [128]
    const float* __restrict__ W_hh,   // [128, 32]
    const float* __restrict__ b_ih,   // [128]
    const float* __restrict__ b_hh,   // [128]
    const float* __restrict__ W_lin,  // [32]
    const float* __restrict__ b_lin,  // [1]
    float* __restrict__ out,          // [B]
    int B)
{
    __shared__ float Hs[4][5][HSTRIDE];   // per-wave: rows 0-3 = batches, row 4 = zeros

    const int lane  = (int)(threadIdx.x & 63u);
    const int wid   = (int)(threadIdx.x >> 6);
    const int col   = lane & 15;          // tile-local col = cell (mod 16) = A-row candidate
    const int grp   = lane >> 4;          // 0..3: k-group AND this lane's batch slot
    const int kbase = grp * 8;

    // zero this wave's H slice (incl. permanent zero row 4)
    float* Hw = &Hs[wid][0][0];
    for (int i = lane; i < 5 * HSTRIDE; i += 64) Hw[i] = 0.0f;
    __builtin_amdgcn_wave_barrier();

    // A-fragment source: A-row = col; live rows are 0,4,8,12 -> storage row col/4, else zero row
    const int srow = ((col & 3) == 0) ? (col >> 2) : 4;
    const float* Aread = &Hs[wid][0][0] + srow * HSTRIDE + kbase;

    // h writeback: this lane's batch row, cells c0, c1
    const int c0 = col, c1 = col + 16;
    float* hw0 = &Hs[wid][0][0] + grp * HSTRIDE + c0;
    float* hw1 = &Hs[wid][0][0] + grp * HSTRIDE + c1;

    // B-fragments (static): tile t covers gate cols 16t + col; k = kbase..kbase+7
    s16x8 bhi[8], blo[8];
    float wih8[8];
    f32x4 biasC[8];
#pragma unroll
    for (int t = 0; t < 8; ++t) {
        const int gr = t * 16 + col;                       // gate row in W (0..127)
        const float* wr = &W_hh[gr * 32 + kbase];
        float4 wa = *reinterpret_cast<const float4*>(wr);
        float4 wb = *reinterpret_cast<const float4*>(wr + 4);
        split_pack(wa, wb, bhi[t], blo[t]);
        wih8[t] = W_ih[gr];
        const float bb = b_ih[gr] + b_hh[gr];
        biasC[t] = f32x4{bb, bb, bb, bb};                  // bias depends on col only
    }

    const int b_glob = blockIdx.x * 16 + wid * 4 + grp;
    const int bc     = b_glob < B ? b_glob : (B - 1);
    const float* xb  = x + (size_t)bc * 512;
    float xt_next = xb[0];

    float cc0 = 0.0f, cc1 = 0.0f;     // cell states for (batch grp, cells c0/c1)
    float h0 = 0.0f, h1 = 0.0f;

    for (int t = 0; t < 512; ++t) {
        const float xt = xt_next;
        xt_next = xb[(t + 1) & 511];                       // prefetch (wraps harmlessly)

        // A-fragments from LDS (h(t-1)); zero rows for non-live A-rows
        float4 ha = *reinterpret_cast<const float4*>(Aread);
        float4 hb = *reinterpret_cast<const float4*>(Aread + 4);
        __builtin_amdgcn_wave_barrier();                   // keep h(t) stores BELOW these reads
        s16x8 ahi, alo;
        split_pack(ha, hb, ahi, alo);

        // gates: 8 tiles x (3-term split MFMA), bias pre-loaded in C
        float g8[8];
#pragma unroll
        for (int tt = 0; tt < 8; ++tt) {
            f32x4 acc = MFMA(ahi, bhi[tt], biasC[tt]);
            acc = MFMA(ahi, blo[tt], acc);
            acc = MFMA(alo, bhi[tt], acc);
            g8[tt] = fmaf(xt, wih8[tt], acc[0]);           // + x-contribution (reg0 = our row)
        }

        // lane-local nonlinearities + cell update (PyTorch order i,f,g,o)
        const float i0 = sigf(g8[0]), i1 = sigf(g8[1]);
        const float f0 = sigf(g8[2]), f1 = sigf(g8[3]);
        const float G0 = tanh_f(g8[4]), G1 = tanh_f(g8[5]);
        const float o0 = sigf(g8[6]), o1 = sigf(g8[7]);

        cc0 = fmaf(f0, cc0, i0 * G0);
        cc1 = fmaf(f1, cc1, i1 * G1);
        h0 = o0 * tanh_f(cc0);
        h1 = o1 * tanh_f(cc1);

        // publish h(t) for next step's A-fragments (wave-private, DS in-order)
        *hw0 = h0;
        *hw1 = h1;
        __builtin_amdgcn_wave_barrier();                   // keep stores BELOW this iter, ABOVE next reads
    }

    // out[b] = sum_cell h[cell] * W_lin[cell] + b_lin  (reduce over 16-lane batch group)
    float part = h0 * W_lin[c0] + h1 * W_lin[c1];
    part += __shfl_xor(part, 1, 64);
    part += __shfl_xor(part, 2, 64);
    part += __shfl_xor(part, 4, 64);
    part += __shfl_xor(part, 8, 64);
    if (col == 0 && b_glob < B) out[b_glob] = part + b_lin[0];
}

extern "C" void kernel_launch(void* const* d_in, const int* in_sizes, int n_in,
                              void* d_out, int out_size, void* d_ws, size_t ws_size,
                              hipStream_t stream) {
    const float* x     = (const float*)d_in[0];
    const float* W_ih  = (const float*)d_in[1];
    const float* W_hh  = (const float*)d_in[2];
    const float* b_ih  = (const float*)d_in[3];
    const float* b_hh  = (const float*)d_in[4];
    const float* W_lin = (const float*)d_in[5];
    const float* b_lin = (const float*)d_in[6];
    float* out = (float*)d_out;

    const int B = in_sizes[0] / 512;          // x is [B, 512, 1]
    const int blocks = (B + 15) / 16;         // 16 batches per 256-thread block (4 waves x 4)

    lstm_mfma_kernel<<<blocks, 256, 0, stream>>>(x, W_ih, W_hh, b_ih, b_hh,
                                                 W_lin, b_lin, out, B);
}

// Round 7
// 202.267 us; speedup vs baseline: 2.4198x; 1.2414x over previous
//
#include <hip/hip_runtime.h>

// LSTM B=4096, T=512, I=1, H=32 — MFMA, round 7.
//
// Structure (verified r6): one wave = 4 batches at D-rows {0,4,8,12} of
// mfma_f32_16x16x32_bf16. Lane l owns batch (l>>4), cells (l&15), (l&15)+16;
// tiles 0..7 put i,f,g,o for those cells in the SAME lane (reg 0) -> cell
// update is lane-local. h redistribution via wave-private LDS.
//
// Round-7 changes (stall/VALU attack at 1 wave/SIMD):
//  1. acc[8] + three separate unrolled MFMA passes -> 8-way independent MFMA
//     streams (r6's VGPR=72 showed the compiler serialized the 3-chains).
//  2. h stored in LDS as bf16 hi/lo u16 arrays: writer splits (cheap, 2 cells),
//     reader ds_read_b128 IS the A-fragment (no per-step split on the
//     read->MFMA critical path). Stride 48 u16 = 16B-aligned, bank-spread.
//  3. x double-buffered in registers (2 x float4 per 8 steps, prefetched one
//     chunk ahead) -> no per-step global load/addressing.
//
// Precision (unchanged): 3-term split Ahi*Bhi + Ahi*Blo + Alo*Bhi, bias in C.

typedef float f32x4 __attribute__((ext_vector_type(4)));
typedef short s16x8 __attribute__((ext_vector_type(8)));
typedef int   i32x4 __attribute__((ext_vector_type(4)));

union PK { i32x4 i; s16x8 s; };

#define L2E 1.44269504088896340736f
#define MFMA(a, b, c) __builtin_amdgcn_mfma_f32_16x16x32_bf16((a), (b), (c), 0, 0, 0)

// one u32 = [bf16(b)<<16 | bf16(a)]  (truncation; residual goes to lo part)
__device__ __forceinline__ unsigned bfpack(float a, float b) {
    return __builtin_amdgcn_perm(__float_as_uint(b), __float_as_uint(a), 0x07060302u);
}
__device__ __forceinline__ float hi_f(float f) {
    return __uint_as_float(__float_as_uint(f) & 0xFFFF0000u);
}
__device__ __forceinline__ void split_pack(float4 A, float4 B, s16x8& hi, s16x8& lo) {
    PK h, l;
    h.i = i32x4{(int)bfpack(A.x, A.y), (int)bfpack(A.z, A.w),
                (int)bfpack(B.x, B.y), (int)bfpack(B.z, B.w)};
    l.i = i32x4{(int)bfpack(A.x - hi_f(A.x), A.y - hi_f(A.y)),
                (int)bfpack(A.z - hi_f(A.z), A.w - hi_f(A.w)),
                (int)bfpack(B.x - hi_f(B.x), B.y - hi_f(B.y)),
                (int)bfpack(B.z - hi_f(B.z), B.w - hi_f(B.w))};
    hi = h.s; lo = l.s;
}

__device__ __forceinline__ float sigf(float x) {
    return __builtin_amdgcn_rcpf(1.0f + __builtin_amdgcn_exp2f(-x * L2E));
}
__device__ __forceinline__ float tanh_f(float x) {
    return fmaf(__builtin_amdgcn_rcpf(1.0f + __builtin_amdgcn_exp2f(x * (-2.0f * L2E))),
                2.0f, -1.0f);
}

#define HSTR 48   // u16 row stride: row base = 96B (16B-aligned), banks spread

__global__ __launch_bounds__(256, 1) void lstm_mfma_kernel(
    const float* __restrict__ x,      // [B, 512]
    const float* __restrict__ W_ih,   // [128]
    const float* __restrict__ W_hh,   // [128, 32]
    const float* __restrict__ b_ih,   // [128]
    const float* __restrict__ b_hh,   // [128]
    const float* __restrict__ W_lin,  // [32]
    const float* __restrict__ b_lin,  // [1]
    float* __restrict__ out,          // [B]
    int B)
{
    __shared__ unsigned short Hhi[4][5][HSTR];  // [wave][4 batches + zero row][HSTR]
    __shared__ unsigned short Hlo[4][5][HSTR];

    const int lane  = (int)(threadIdx.x & 63u);
    const int wid   = (int)(threadIdx.x >> 6);
    const int col   = lane & 15;          // cell (mod 16) = A-row candidate
    const int grp   = lane >> 4;          // batch slot AND k-group
    const int kbase = grp * 8;

    // zero this wave's LDS slice (incl. permanent zero row 4)
    {
        unsigned short* ph = &Hhi[wid][0][0];
        unsigned short* pl = &Hlo[wid][0][0];
        for (int i = lane; i < 5 * HSTR; i += 64) { ph[i] = 0; pl[i] = 0; }
    }
    __builtin_amdgcn_wave_barrier();

    // A-fragment read: A-row = col; live rows 0,4,8,12 -> batch col/4, else zero row
    const int srow = ((col & 3) == 0) ? (col >> 2) : 4;
    const unsigned short* Ahi_p = &Hhi[wid][srow][kbase];   // 16B-aligned
    const unsigned short* Alo_p = &Hlo[wid][srow][kbase];

    // h writeback: this lane's batch row, cells c0, c1 (bf16 hi/lo u16 stores)
    const int c0 = col, c1 = col + 16;
    unsigned short* whi0 = &Hhi[wid][grp][c0];
    unsigned short* whi1 = &Hhi[wid][grp][c1];
    unsigned short* wlo0 = &Hlo[wid][grp][c0];
    unsigned short* wlo1 = &Hlo[wid][grp][c1];

    // B-fragments (static): tile t covers gate col 16t + col; k = kbase..kbase+7
    s16x8 bhi[8], blo[8];
    float wih8[8];
    f32x4 biasC[8];
#pragma unroll
    for (int t = 0; t < 8; ++t) {
        const int gr = t * 16 + col;                       // gate row (0..127)
        const float* wr = &W_hh[gr * 32 + kbase];
        float4 wa = *reinterpret_cast<const float4*>(wr);
        float4 wb = *reinterpret_cast<const float4*>(wr + 4);
        split_pack(wa, wb, bhi[t], blo[t]);
        wih8[t] = W_ih[gr];
        const float bb = b_ih[gr] + b_hh[gr];
        biasC[t] = f32x4{bb, bb, bb, bb};
    }

    const int b_glob = blockIdx.x * 16 + wid * 4 + grp;
    const int bc     = b_glob < B ? b_glob : (B - 1);
    const float* xb  = x + (size_t)bc * 512;

    // x double-buffer: 8 timesteps per chunk, next chunk prefetched at chunk start
    float4 xA = *reinterpret_cast<const float4*>(xb);
    float4 xB = *reinterpret_cast<const float4*>(xb + 4);

    float cc0 = 0.0f, cc1 = 0.0f, h0 = 0.0f, h1 = 0.0f;

    for (int tc = 0; tc < 64; ++tc) {
        const int nbase = ((tc + 1) & 63) * 8;             // wraps harmlessly
        const float4 nA = *reinterpret_cast<const float4*>(xb + nbase);
        const float4 nB = *reinterpret_cast<const float4*>(xb + nbase + 4);
        const float xts[8] = {xA.x, xA.y, xA.z, xA.w, xB.x, xB.y, xB.z, xB.w};

#pragma unroll
        for (int s = 0; s < 8; ++s) {
            const float xt = xts[s];

            // A-fragments: ds_read_b128 IS the bf16 fragment (pair order k,k+1)
            const s16x8 ahi = *reinterpret_cast<const s16x8*>(Ahi_p);
            const s16x8 alo = *reinterpret_cast<const s16x8*>(Alo_p);
            __builtin_amdgcn_wave_barrier();               // keep h stores below reads

            // three passes of 8 INDEPENDENT MFMAs (dependent pairs 8 apart)
            f32x4 acc[8];
#pragma unroll
            for (int tt = 0; tt < 8; ++tt) acc[tt] = MFMA(ahi, bhi[tt], biasC[tt]);
#pragma unroll
            for (int tt = 0; tt < 8; ++tt) acc[tt] = MFMA(ahi, blo[tt], acc[tt]);
#pragma unroll
            for (int tt = 0; tt < 8; ++tt) acc[tt] = MFMA(alo, bhi[tt], acc[tt]);

            float g8[8];
#pragma unroll
            for (int tt = 0; tt < 8; ++tt) g8[tt] = fmaf(xt, wih8[tt], acc[tt][0]);

            // lane-local gates + cell update (PyTorch order i,f,g,o)
            const float i0 = sigf(g8[0]), i1 = sigf(g8[1]);
            const float f0 = sigf(g8[2]), f1 = sigf(g8[3]);
            const float G0 = tanh_f(g8[4]), G1 = tanh_f(g8[5]);
            const float o0 = sigf(g8[6]), o1 = sigf(g8[7]);

            cc0 = fmaf(f0, cc0, i0 * G0);
            cc1 = fmaf(f1, cc1, i1 * G1);
            h0 = o0 * tanh_f(cc0);
            h1 = o1 * tanh_f(cc1);

            // bf16 hi/lo split on the WRITE side (2 cells, cheap)
            const unsigned u0 = __float_as_uint(h0);
            const float l0 = h0 - __uint_as_float(u0 & 0xFFFF0000u);
            const unsigned u1 = __float_as_uint(h1);
            const float l1 = h1 - __uint_as_float(u1 & 0xFFFF0000u);
            *whi0 = (unsigned short)(u0 >> 16);
            *whi1 = (unsigned short)(u1 >> 16);
            *wlo0 = (unsigned short)(__float_as_uint(l0) >> 16);
            *wlo1 = (unsigned short)(__float_as_uint(l1) >> 16);
            __builtin_amdgcn_wave_barrier();               // stores above next reads
        }
        xA = nA; xB = nB;
    }

    // out[b] = sum_cell h[cell]*W_lin[cell] + b_lin (reduce over 16-lane group)
    float part = h0 * W_lin[c0] + h1 * W_lin[c1];
    part += __shfl_xor(part, 1, 64);
    part += __shfl_xor(part, 2, 64);
    part += __shfl_xor(part, 4, 64);
    part += __shfl_xor(part, 8, 64);
    if (col == 0 && b_glob < B) out[b_glob] = part + b_lin[0];
}

extern "C" void kernel_launch(void* const* d_in, const int* in_sizes, int n_in,
                              void* d_out, int out_size, void* d_ws, size_t ws_size,
                              hipStream_t stream) {
    const float* x     = (const float*)d_in[0];
    const float* W_ih  = (const float*)d_in[1];
    const float* W_hh  = (const float*)d_in[2];
    const float* b_ih  = (const float*)d_in[3];
    const float* b_hh  = (const float*)d_in[4];
    const float* W_lin = (const float*)d_in[5];
    const float* b_lin = (const float*)d_in[6];
    float* out = (float*)d_out;

    const int B = in_sizes[0] / 512;          // x is [B, 512, 1]
    const int blocks = (B + 15) / 16;         // 16 batches per 256-thread block

    lstm_mfma_kernel<<<blocks, 256, 0, stream>>>(x, W_ih, W_hh, b_ih, b_hh,
                                                 W_lin, b_lin, out, B);
}

// Round 8
// 169.528 us; speedup vs baseline: 2.8872x; 1.1931x over previous
//
#include <hip/hip_runtime.h>

// LSTM B=4096, T=512, I=1, H=32 — MFMA, round 8.
//
// Mapping (verified r6/r7): mfma_f32_16x16x32_bf16; lane l = batch (l>>4),
// cells (l&15), (l&15)+16; 8 gate tiles put i,f,g,o for those cells in the
// same lane. NEW in r8:
//  1. hi/lo split moved into A-ROWS: rows {0,4,8,12}=h_hi, {1,5,9,13}=h_lo.
//     D-reg0 = Ahi*B, D-reg1 = Alo*B (same lane). Two B-passes (Bhi with
//     bias in C reg0, Blo accumulating) = 16 MFMAs (was 24), full 4-term
//     product precision. g = acc[0]+acc[1]+xt*wih.
//  2. k-permutation c <-> k=2*(c&15)+(c>>4): lane's two cells are one u32
//     bf16 pair -> h publish = 2x ds_write_b32, A fetch = 1x ds_read_b128
//     (DS ops 6 -> 3). B pre-packed with the same permutation (cancels).
//  3. Gate input scales (-log2e / -2log2e) folded into W_hh/W_ih/bias.
//
// Rows 2,3 mod 4 of A alias batch-0 data; their D regs (2,3) are never read.

typedef float f32x4 __attribute__((ext_vector_type(4)));
typedef short s16x8 __attribute__((ext_vector_type(8)));

#define L2E 1.44269504088896340736f
#define MFMA(a, b, c) __builtin_amdgcn_mfma_f32_16x16x32_bf16((a), (b), (c), 0, 0, 0)

// u32 = [bf16(b) << 16 | bf16(a)]  (truncation; residual captured separately)
__device__ __forceinline__ unsigned bfpack(float a, float b) {
    return __builtin_amdgcn_perm(__float_as_uint(b), __float_as_uint(a), 0x07060302u);
}
__device__ __forceinline__ float hi_f(float f) {
    return __uint_as_float(__float_as_uint(f) & 0xFFFF0000u);
}
__device__ __forceinline__ float sig_pre(float t) {   // t = -L2E*g already
    return __builtin_amdgcn_rcpf(1.0f + __builtin_amdgcn_exp2f(t));
}
__device__ __forceinline__ float tanh_pre(float t) {  // t = -2*L2E*g already
    return fmaf(__builtin_amdgcn_rcpf(1.0f + __builtin_amdgcn_exp2f(t)), 2.0f, -1.0f);
}

#define HSTR 36   // u32 row stride: 144B rows (16B-aligned), banks spread

__global__ __launch_bounds__(256, 1) void lstm_mfma_kernel(
    const float* __restrict__ x,      // [B, 512]
    const float* __restrict__ W_ih,   // [128]
    const float* __restrict__ W_hh,   // [128, 32]
    const float* __restrict__ b_ih,   // [128]
    const float* __restrict__ b_hh,   // [128]
    const float* __restrict__ W_lin,  // [32]
    const float* __restrict__ b_lin,  // [1]
    float* __restrict__ out,          // [B]
    int B)
{
    // rows: b0hi,b0lo,b1hi,b1lo,b2hi,b2lo,b3hi,b3lo  (per wave)
    __shared__ unsigned Hs[4][8][HSTR];

    const int lane = (int)(threadIdx.x & 63u);
    const int wid  = (int)(threadIdx.x >> 6);
    const int col  = lane & 15;           // cell (mod 16) = tile col = A-row idx
    const int grp  = lane >> 4;           // this lane's batch slot & k-group

    // A-fragment source row: col%4==0 -> hi(batch col/4); ==1 -> lo(batch col/4);
    // ==2/3 -> alias batch0 hi/lo (feeds D regs 2,3 which are never read)
    const int m4   = col & 3;
    const int srow = (m4 == 0) ? 2 * (col >> 2)
                   : (m4 == 1) ? 2 * (col >> 2) + 1
                   : (m4 == 2) ? 0 : 1;
    const unsigned* Aread = &Hs[wid][srow][grp * 4];     // 16B-aligned

    // h publish: one u32 (bf16 pair of cells c0,c1) per hi/lo row
    unsigned* whi = &Hs[wid][2 * grp + 0][col];
    unsigned* wlo = &Hs[wid][2 * grp + 1][col];

    // init: zero all read slots (h(0)=0) — each lane's own slots cover them
    *whi = 0u; *wlo = 0u;
    __builtin_amdgcn_wave_barrier();

    // B-fragments, scales folded. Tile t: gate row gr = 16t+col.
    // u32 j of the fragment = pair(cell grp*4+j, cell grp*4+j+16)  [k-perm]
    s16x8 bhi[8], blo[8];
    float wihs[8];
    f32x4 biasC[8];
#pragma unroll
    for (int t = 0; t < 8; ++t) {
        const int gr = t * 16 + col;
        const float sc = (t == 4 || t == 5) ? (-2.0f * L2E) : (-L2E);
        const float* wr = &W_hh[gr * 32];
        float4 wA = *reinterpret_cast<const float4*>(&wr[grp * 4]);       // cells g4+0..3
        float4 wB = *reinterpret_cast<const float4*>(&wr[grp * 4 + 16]);  // cells g4+16..19
        const float a0 = wA.x * sc, a1 = wA.y * sc, a2 = wA.z * sc, a3 = wA.w * sc;
        const float b0 = wB.x * sc, b1 = wB.y * sc, b2 = wB.z * sc, b3 = wB.w * sc;
        union { unsigned u[4]; s16x8 s; } H, L;
        H.u[0] = bfpack(a0, b0); H.u[1] = bfpack(a1, b1);
        H.u[2] = bfpack(a2, b2); H.u[3] = bfpack(a3, b3);
        L.u[0] = bfpack(a0 - hi_f(a0), b0 - hi_f(b0));
        L.u[1] = bfpack(a1 - hi_f(a1), b1 - hi_f(b1));
        L.u[2] = bfpack(a2 - hi_f(a2), b2 - hi_f(b2));
        L.u[3] = bfpack(a3 - hi_f(a3), b3 - hi_f(b3));
        bhi[t] = H.s; blo[t] = L.s;
        wihs[t] = W_ih[gr] * sc;
        const float bb = (b_ih[gr] + b_hh[gr]) * sc;
        biasC[t] = f32x4{bb, 0.0f, 0.0f, 0.0f};         // bias only in reg0 (hi row)
    }

    const int b_glob = blockIdx.x * 16 + wid * 4 + grp;
    const int bc     = b_glob < B ? b_glob : (B - 1);
    const float* xb  = x + (size_t)bc * 512;

    float4 xA = *reinterpret_cast<const float4*>(xb);
    float4 xB = *reinterpret_cast<const float4*>(xb + 4);

    float cc0 = 0.0f, cc1 = 0.0f, h0 = 0.0f, h1 = 0.0f;

    for (int tc = 0; tc < 64; ++tc) {
        const int nbase = ((tc + 1) & 63) * 8;
        const float4 nA = *reinterpret_cast<const float4*>(xb + nbase);
        const float4 nB = *reinterpret_cast<const float4*>(xb + nbase + 4);
        const float xts[8] = {xA.x, xA.y, xA.z, xA.w, xB.x, xB.y, xB.z, xB.w};

#pragma unroll
        for (int s = 0; s < 8; ++s) {
            const float xt = xts[s];

            // one b128: this lane's A-row (hi OR lo of one batch), k-pairs direct
            const s16x8 afrag = *reinterpret_cast<const s16x8*>(Aread);
            __builtin_amdgcn_wave_barrier();

            // pass 1: Bhi (bias in C reg0); pass 2: Blo accumulate.
            // reg0 = Ahi*B, reg1 = Alo*B -> full 4-term product after both passes.
            f32x4 acc[8];
#pragma unroll
            for (int t = 0; t < 8; ++t) acc[t] = MFMA(afrag, bhi[t], biasC[t]);
#pragma unroll
            for (int t = 0; t < 8; ++t) acc[t] = MFMA(afrag, blo[t], acc[t]);

            float g8[8];
#pragma unroll
            for (int t = 0; t < 8; ++t)
                g8[t] = fmaf(xt, wihs[t], acc[t][0] + acc[t][1]);

            // inputs pre-scaled: sig tiles carry -L2E*g, tanh tiles -2L2E*g
            const float i0 = sig_pre(g8[0]), i1 = sig_pre(g8[1]);
            const float f0 = sig_pre(g8[2]), f1 = sig_pre(g8[3]);
            const float G0 = tanh_pre(g8[4]), G1 = tanh_pre(g8[5]);
            const float o0 = sig_pre(g8[6]), o1 = sig_pre(g8[7]);

            cc0 = fmaf(f0, cc0, i0 * G0);
            cc1 = fmaf(f1, cc1, i1 * G1);
            const float tc0 = tanh_pre(cc0 * (-2.0f * L2E));
            const float tc1 = tanh_pre(cc1 * (-2.0f * L2E));
            h0 = o0 * tc0;
            h1 = o1 * tc1;

            // publish h: one u32 pair each for hi and lo rows
            *whi = bfpack(h0, h1);
            *wlo = bfpack(h0 - hi_f(h0), h1 - hi_f(h1));
            __builtin_amdgcn_wave_barrier();
        }
        xA = nA; xB = nB;
    }

    // out[b] = sum_cells h*W_lin + b_lin (reduce over the 16-lane batch group)
    float part = h0 * W_lin[col] + h1 * W_lin[col + 16];
    part += __shfl_xor(part, 1, 64);
    part += __shfl_xor(part, 2, 64);
    part += __shfl_xor(part, 4, 64);
    part += __shfl_xor(part, 8, 64);
    if (col == 0 && b_glob < B) out[b_glob] = part + b_lin[0];
}

extern "C" void kernel_launch(void* const* d_in, const int* in_sizes, int n_in,
                              void* d_out, int out_size, void* d_ws, size_t ws_size,
                              hipStream_t stream) {
    const float* x     = (const float*)d_in[0];
    const float* W_ih  = (const float*)d_in[1];
    const float* W_hh  = (const float*)d_in[2];
    const float* b_ih  = (const float*)d_in[3];
    const float* b_hh  = (const float*)d_in[4];
    const float* W_lin = (const float*)d_in[5];
    const float* b_lin = (const float*)d_in[6];
    float* out = (float*)d_out;

    const int B = in_sizes[0] / 512;          // x is [B, 512, 1]
    const int blocks = (B + 15) / 16;         // 16 batches per 256-thread block

    lstm_mfma_kernel<<<blocks, 256, 0, stream>>>(x, W_ih, W_hh, b_ih, b_hh,
                                                 W_lin, b_lin, out, B);
}

// Round 9
// 145.092 us; speedup vs baseline: 3.3734x; 1.1684x over previous
//
#include <hip/hip_runtime.h>

// LSTM B=4096, T=512, I=1, H=32 — MFMA, round 9: 2-wave cooperative blocks.
//
// Block = 128 threads = 2 waves sharing 4 batches (batch slot g = lane>>4).
// Wave w owns cells col+16w (one cell per lane): its 4 gate tiles
// {w, w+2, w+4, w+6} = i,f,G,o of those cells -> 8 MFMAs/wave/step,
// 10 trans ops/lane-step (half of r8). 2048 waves = 2/SIMD + 4 blocks/CU
// -> the ~400cy per-step latency chain (LDS round-trip + MFMA dep + trans)
// hides under co-resident waves. Per-CU MFMA demand unchanged (64/step).
//
// h exchange: block-shared DOUBLE-BUFFERED LDS, one __syncthreads per step
// (step reads buf p, writes buf p^1; barrier orders write->read across waves;
// write-after-read of buf p is safe because p-writes happen the NEXT step,
// after the barrier). Layout/k-perm/4-term hi/lo precision = verified r8:
//   A-row r: r=2b -> batch b h_hi, r=2b+1 -> h_lo (rows r%4 in {2,3} alias
//   rows 0/1, feeding D regs 2,3 which are never read).
//   k-perm: cell c <-> k = 2*(c&15) + (c>>4); gate scales folded into W/bias.

typedef float f32x4 __attribute__((ext_vector_type(4)));
typedef short s16x8 __attribute__((ext_vector_type(8)));

#define L2E 1.44269504088896340736f
#define MFMA(a, b, c) __builtin_amdgcn_mfma_f32_16x16x32_bf16((a), (b), (c), 0, 0, 0)

__device__ __forceinline__ unsigned bfpack(float a, float b) {
    return __builtin_amdgcn_perm(__float_as_uint(b), __float_as_uint(a), 0x07060302u);
}
__device__ __forceinline__ float hi_f(float f) {
    return __uint_as_float(__float_as_uint(f) & 0xFFFF0000u);
}
__device__ __forceinline__ float sig_pre(float t) {   // t = -L2E*g
    return __builtin_amdgcn_rcpf(1.0f + __builtin_amdgcn_exp2f(t));
}
__device__ __forceinline__ float tanh_pre(float t) {  // t = -2*L2E*g
    return fmaf(__builtin_amdgcn_rcpf(1.0f + __builtin_amdgcn_exp2f(t)), 2.0f, -1.0f);
}

#define RSTR 40   // u16 stride per (batch,hi/lo) row: 80B, 16B-aligned, banks spread

__global__ __launch_bounds__(128, 2) void lstm_mfma_kernel(
    const float* __restrict__ x,      // [B, 512]
    const float* __restrict__ W_ih,   // [128]
    const float* __restrict__ W_hh,   // [128, 32]
    const float* __restrict__ b_ih,   // [128]
    const float* __restrict__ b_hh,   // [128]
    const float* __restrict__ W_lin,  // [32]
    const float* __restrict__ b_lin,  // [1]
    float* __restrict__ out,          // [B]
    int B)
{
    __shared__ unsigned short Hb[2][8][RSTR];   // [buf][batch*2 + hi/lo][RSTR]
    __shared__ float plds[4][2];

    const int tid  = (int)threadIdx.x;
    const int w    = tid >> 6;            // wave 0/1 -> cells col / col+16
    const int lane = tid & 63;
    const int col  = lane & 15;           // tile col
    const int g    = lane >> 4;           // batch slot & k-group

    // zero both buffers (h(0) = 0)
    for (int i = tid; i < 2 * 8 * RSTR; i += 128)
        ((unsigned short*)Hb)[i] = 0;

    // A-fragment read row: col%4==0 -> hi(batch col/4); ==1 -> lo; ==2/3 -> rows 0/1
    const int m4   = col & 3;
    const int rrow = (m4 == 0) ? 2 * (col >> 2)
                   : (m4 == 1) ? 2 * (col >> 2) + 1
                   : (m4 - 2);
    const unsigned short* Ard0 = &Hb[0][rrow][8 * g];   // 16B-aligned
    const unsigned short* Ard1 = &Hb[1][rrow][8 * g];

    // h publish: this lane's cell -> u16 at k = 2*col + w, rows (g,hi),(g,lo)
    unsigned short* Whi0 = &Hb[0][2 * g + 0][2 * col + w];
    unsigned short* Wlo0 = &Hb[0][2 * g + 1][2 * col + w];
    unsigned short* Whi1 = &Hb[1][2 * g + 0][2 * col + w];
    unsigned short* Wlo1 = &Hb[1][2 * g + 1][2 * col + w];

    // B-fragments for this wave's 4 tiles (t = w+2j; j = i,f,G,o), scales folded.
    // u32 jj of fragment = pair(cell g*4+jj, cell g*4+jj+16)  [k-perm]
    s16x8 bhi[4], blo[4];
    float wihs[4];
    f32x4 biasC[4];
#pragma unroll
    for (int j = 0; j < 4; ++j) {
        const int t  = w + 2 * j;
        const int gr = t * 16 + col;
        const float sc = (j == 2) ? (-2.0f * L2E) : (-L2E);
        const float* wr = &W_hh[gr * 32];
        float4 wA = *reinterpret_cast<const float4*>(&wr[g * 4]);
        float4 wB = *reinterpret_cast<const float4*>(&wr[g * 4 + 16]);
        const float a0 = wA.x * sc, a1 = wA.y * sc, a2 = wA.z * sc, a3 = wA.w * sc;
        const float b0 = wB.x * sc, b1 = wB.y * sc, b2 = wB.z * sc, b3 = wB.w * sc;
        union { unsigned u[4]; s16x8 s; } H, L;
        H.u[0] = bfpack(a0, b0); H.u[1] = bfpack(a1, b1);
        H.u[2] = bfpack(a2, b2); H.u[3] = bfpack(a3, b3);
        L.u[0] = bfpack(a0 - hi_f(a0), b0 - hi_f(b0));
        L.u[1] = bfpack(a1 - hi_f(a1), b1 - hi_f(b1));
        L.u[2] = bfpack(a2 - hi_f(a2), b2 - hi_f(b2));
        L.u[3] = bfpack(a3 - hi_f(a3), b3 - hi_f(b3));
        bhi[j] = H.s; blo[j] = L.s;
        wihs[j] = W_ih[gr] * sc;
        const float bb = (b_ih[gr] + b_hh[gr]) * sc;
        biasC[j] = f32x4{bb, 0.0f, 0.0f, 0.0f};        // bias only in reg0 (hi row)
    }

    const int b_glob = blockIdx.x * 4 + g;
    const int bc     = b_glob < B ? b_glob : (B - 1);
    const float* xb  = x + (size_t)bc * 512;

    float4 xA = *reinterpret_cast<const float4*>(xb);
    float4 xB = *reinterpret_cast<const float4*>(xb + 4);

    float cc = 0.0f, hh = 0.0f;
    __syncthreads();                                    // zero-init visible

    for (int tc = 0; tc < 64; ++tc) {
        const int nbase = ((tc + 1) & 63) * 8;
        const float4 nA = *reinterpret_cast<const float4*>(xb + nbase);
        const float4 nB = *reinterpret_cast<const float4*>(xb + nbase + 4);
        const float xts[8] = {xA.x, xA.y, xA.z, xA.w, xB.x, xB.y, xB.z, xB.w};

#pragma unroll
        for (int s = 0; s < 8; ++s) {
            const float xt = xts[s];

            // even global step reads buf0 (h starts in buf0), writes buf1
            const s16x8 af = *reinterpret_cast<const s16x8*>((s & 1) ? Ard1 : Ard0);

            f32x4 acc[4];
#pragma unroll
            for (int j = 0; j < 4; ++j) acc[j] = MFMA(af, bhi[j], biasC[j]);
#pragma unroll
            for (int j = 0; j < 4; ++j) acc[j] = MFMA(af, blo[j], acc[j]);

            float gt[4];
#pragma unroll
            for (int j = 0; j < 4; ++j)
                gt[j] = fmaf(xt, wihs[j], acc[j][0] + acc[j][1]);

            const float i_ = sig_pre(gt[0]);
            const float f_ = sig_pre(gt[1]);
            const float G_ = tanh_pre(gt[2]);
            const float o_ = sig_pre(gt[3]);

            cc = fmaf(f_, cc, i_ * G_);
            hh = o_ * tanh_pre(cc * (-2.0f * L2E));

            // publish h (hi + residual-lo bf16) to the OTHER buffer
            const unsigned uh = __float_as_uint(hh);
            const float lo = hh - __uint_as_float(uh & 0xFFFF0000u);
            *((s & 1) ? Whi0 : Whi1) = (unsigned short)(uh >> 16);
            *((s & 1) ? Wlo0 : Wlo1) = (unsigned short)(__float_as_uint(lo) >> 16);
            __syncthreads();
        }
        xA = nA; xB = nB;
    }

    // out[b] = sum_cells h*W_lin + b_lin: 16-lane reduce, then cross-wave via LDS
    float part = hh * W_lin[col + 16 * w];
    part += __shfl_xor(part, 1, 64);
    part += __shfl_xor(part, 2, 64);
    part += __shfl_xor(part, 4, 64);
    part += __shfl_xor(part, 8, 64);
    if (col == 0) plds[g][w] = part;
    __syncthreads();
    if (w == 0 && col == 0 && b_glob < B)
        out[b_glob] = plds[g][0] + plds[g][1] + b_lin[0];
}

extern "C" void kernel_launch(void* const* d_in, const int* in_sizes, int n_in,
                              void* d_out, int out_size, void* d_ws, size_t ws_size,
                              hipStream_t stream) {
    const float* x     = (const float*)d_in[0];
    const float* W_ih  = (const float*)d_in[1];
    const float* W_hh  = (const float*)d_in[2];
    const float* b_ih  = (const float*)d_in[3];
    const float* b_hh  = (const float*)d_in[4];
    const float* W_lin = (const float*)d_in[5];
    const float* b_lin = (const float*)d_in[6];
    float* out = (float*)d_out;

    const int B = in_sizes[0] / 512;          // x is [B, 512, 1]
    const int blocks = (B + 3) / 4;           // 4 batches per 128-thread block

    lstm_mfma_kernel<<<blocks, 128, 0, stream>>>(x, W_ih, W_hh, b_ih, b_hh,
                                                 W_lin, b_lin, out, B);
}